// Round 3
// baseline (10580.458 us; speedup 1.0000x reference)
//
#include <hip/hip_runtime.h>
#include <hip/hip_bf16.h>

#define B_   256
#define T_   512
#define D_   64
#define H_   1024
#define NG   4096   // 4*H
#define KTOT 1088   // D + H
#define WPAD 1096   // +8 bf16 pad

typedef __attribute__((ext_vector_type(8)))  short short8;
typedef __attribute__((ext_vector_type(16))) float f32x16;

static __device__ __forceinline__ float tanh_clamped(float u) {
  u = fminf(fmaxf(u, -15.0f), 15.0f);
  float e = __expf(-2.0f * u);
  return (1.0f - e) / (1.0f + e);
}
static __device__ __forceinline__ unsigned short f2bf(float f) {
  union { float f; unsigned int u; } v; v.f = f;
  unsigned int r = (v.u + 0x7FFFu + ((v.u >> 16) & 1u)) >> 16; // RNE
  return (unsigned short)r;
}

__global__ void k_zero_flags(int* flags) {
  int gid = blockIdx.x * 256 + threadIdx.x;
  if (gid < 4096) flags[gid] = 0;
}

// Pack [Wx; Wh] -> Wp[n][k] bf16, n gate-interleaved: n = 4*j + gate, orig col = gate*1024 + j
__global__ void k_pack_w(const float* __restrict__ Wx, const float* __restrict__ Wh,
                         unsigned short* __restrict__ Wp) {
  __shared__ float tile[64][65];
  int nt = blockIdx.x & 63;   // 64 n-tiles
  int kt = blockIdx.x >> 6;   // 17 k-tiles
  int tx = threadIdx.x & 63, ty = threadIdx.x >> 6;
#pragma unroll
  for (int i = 0; i < 16; ++i) {
    int kl = i * 4 + ty;
    int k  = kt * 64 + kl;
    int n  = nt * 64 + tx;
    int oc = ((n & 3) << 10) | (n >> 2);
    float v = (k < D_) ? Wx[k * NG + oc] : Wh[(k - D_) * NG + oc];
    tile[kl][tx] = v;
  }
  __syncthreads();
#pragma unroll
  for (int i = 0; i < 16; ++i) {
    int nl = i * 4 + ty;
    int kl = tx;
    Wp[(size_t)(nt * 64 + nl) * KTOT + kt * 64 + kl] = f2bf(tile[kl][nl]);
  }
}

// Pack x (B,T,64) fp32 -> xbt[t][kk][b][8] bf16 (A-fragment friendly)
__global__ void k_pack_x(const float* __restrict__ x, unsigned short* __restrict__ xbt) {
  int gid = blockIdx.x * 256 + threadIdx.x;  // 1,048,576 chunks
  int b  = gid & 255;
  int kk = (gid >> 8) & 7;
  int t  = gid >> 11;
  const float* src = x + ((size_t)b * T_ + t) * 64 + kk * 8;
  short8 v;
#pragma unroll
  for (int i = 0; i < 8; ++i) v[i] = (short)f2bf(src[i]);
  *(short8*)(xbt + (size_t)gid * 8) = v;
}

__launch_bounds__(256, 1)
__global__ void k_scan(const unsigned short* __restrict__ Wp,
                       const unsigned short* __restrict__ xbt,
                       unsigned short* __restrict__ hbt,   // [2][128][256][8] bf16
                       float* __restrict__ hf,             // [256][1024] fp32 (t=511)
                       const float* __restrict__ bias,
                       int* __restrict__ flags) {
  __shared__ unsigned short Wl[64 * WPAD];  // 140,288 B
  const int tid  = threadIdx.x;
  const int bid  = blockIdx.x;
  const int m    = bid >> 6;     // 4 m-groups of 64 rows
  const int nt   = bid & 63;     // 64 interleaved-col tiles
  const int n0   = nt * 64;
  const int wave = tid >> 6;
  const int lane = tid & 63;
  const int wr = wave >> 1, wc = wave & 1;

  // Stage this block's 64 W columns into LDS (once)
  for (int i = tid; i < 64 * (KTOT / 8); i += 256) {
    int c  = i / (KTOT / 8);
    int kk = i - c * (KTOT / 8);
    short8 v = *(const short8*)(Wp + (size_t)(n0 + c) * KTOT + kk * 8);
    *(short8*)((char*)Wl + c * (WPAD * 2) + kk * 16) = v;
  }
  __syncthreads();

  const int khalf = lane >> 5;                 // 0/1: k-subblock of fragment
  const int rowA  = m * 64 + wr * 32 + (lane & 31);
  const int colB  = wc * 32 + (lane & 31);     // LDS-local col
  const int n     = n0 + colB;
  const int oc    = ((n & 3) << 10) | (n >> 2);
  const float bv  = bias[oc];
  const int s     = lane & 3;                  // gate: 0=i 1=f 2=g 3=o
  const int jH    = n >> 2;
  const char* WlB = (const char*)Wl + colB * (WPAD * 2) + khalf * 16;

  float c_state[16];
#pragma unroll
  for (int r = 0; r < 16; ++r) c_state[r] = 0.0f;

  // distributed flags: 64B-spaced, one per block, per m-group
  int* myflag = flags + (m * 64 + nt) * 16;
  int* pollp  = flags + (m * 64 + lane) * 16;

  for (int t = 0; t < T_; ++t) {
    f32x16 acc;
#pragma unroll
    for (int r = 0; r < 16; ++r) acc[r] = bv;

    // x-contribution (independent of h -> overlaps with waiting)
#pragma unroll
    for (int kt = 0; kt < 4; ++kt) {
      int kkx = t * 8 + kt * 2 + khalf;
      short8 a  = *(const short8*)(xbt + (size_t)kkx * 2048 + rowA * 8);
      short8 b8 = *(const short8*)(WlB + kt * 32);
      acc = __builtin_amdgcn_mfma_f32_32x32x16_bf16(a, b8, acc, 0, 0, 0);
    }

    if (t > 0) {
      // wave 0: each lane polls one producer's flag; exit when all >= t
      if (wave == 0) {
        for (;;) {
          int v = __hip_atomic_load(pollp, __ATOMIC_RELAXED, __HIP_MEMORY_SCOPE_AGENT);
          if (__all(v >= t)) break;
          __builtin_amdgcn_s_sleep(1);
        }
      }
      __syncthreads();
      __builtin_amdgcn_fence(__ATOMIC_ACQUIRE, "agent");
      const unsigned short* hsrc = hbt + (size_t)((t + 1) & 1) * 128 * 2048;

      // issue ALL 64 h-fragment loads, then hard-stop the scheduler from
      // sinking them past this point: 256 VGPRs of A stay in flight.
      short8 aH[64];
#pragma unroll
      for (int j = 0; j < 64; ++j)
        aH[j] = *(const short8*)(hsrc + (size_t)(2 * j + khalf) * 2048 + rowA * 8);
      __builtin_amdgcn_sched_barrier(0);

      f32x16 acc1;
#pragma unroll
      for (int r = 0; r < 16; ++r) acc1[r] = 0.0f;
#pragma unroll
      for (int j = 0; j < 64; j += 2) {
        short8 b0 = *(const short8*)(WlB + 128 + j * 32);
        short8 b1 = *(const short8*)(WlB + 128 + (j + 1) * 32);
        acc  = __builtin_amdgcn_mfma_f32_32x32x16_bf16(aH[j],     b0, acc,  0, 0, 0);
        acc1 = __builtin_amdgcn_mfma_f32_32x32x16_bf16(aH[j + 1], b1, acc1, 0, 0, 0);
      }
#pragma unroll
      for (int r = 0; r < 16; ++r) acc[r] += acc1[r];
    }

    // gates + state update; lanes 4j..4j+3 hold i,f,g,o of (row, j)
    // single-exp path: sigmoid(z) = 0.5*(1+tanh(z/2))
    unsigned short* hdst = hbt + (size_t)(t & 1) * 128 * 2048;
#pragma unroll
    for (int r = 0; r < 16; ++r) {
      float z  = acc[r];
      float u  = (s == 2) ? z : 0.5f * z;
      float tv = tanh_clamped(u);
      float av = (s == 2) ? tv : 0.5f * (1.0f + tv);
      float x1 = __shfl_xor(av, 1);
      float x2 = __shfl_xor(av, 2);
      float x3 = __shfl_xor(av, 3);
      float i_ = (s == 0) ? av : (s == 1) ? x1 : (s == 2) ? x2 : x3;
      float f_ = (s == 1) ? av : (s == 0) ? x1 : (s == 3) ? x2 : x3;
      float g_ = (s == 2) ? av : (s == 3) ? x1 : (s == 0) ? x2 : x3;
      float o_ = (s == 3) ? av : (s == 2) ? x1 : (s == 1) ? x2 : x3;
      float cn = f_ * c_state[r] + i_ * g_;
      c_state[r] = cn;
      float hn = o_ * tanh_clamped(cn);
      if (s == 0) {
        int row = m * 64 + wr * 32 + ((r & 3) + 8 * (r >> 2) + 4 * khalf);
        if (t < T_ - 1) {
          hdst[(size_t)(jH >> 3) * 2048 + row * 8 + (jH & 7)] = f2bf(hn);
        } else {
          hf[(size_t)row * H_ + jH] = hn;
        }
      }
    }

    if (t < T_ - 1) {
      __syncthreads();  // all waves' h stores drained before release
      if (tid == 0) {
        __builtin_amdgcn_fence(__ATOMIC_RELEASE, "agent");
        __hip_atomic_store(myflag, t + 1, __ATOMIC_RELAXED, __HIP_MEMORY_SCOPE_AGENT);
      }
    }
  }
}

__global__ void k_head(const float* __restrict__ hf, const float* __restrict__ Wr,
                       const float* __restrict__ br, float* __restrict__ out) {
  int bf = blockIdx.x;            // b*8 + f
  int b = bf >> 3, f = bf & 7;
  int lane = threadIdx.x;
  float s0 = 0.f, s1 = 0.f, s2 = 0.f;
  for (int j = lane; j < H_; j += 64) {
    float h = hf[(size_t)b * H_ + j];
    const float* w = Wr + ((size_t)f * H_ + j) * 3;
    s0 = fmaf(h, w[0], s0); s1 = fmaf(h, w[1], s1); s2 = fmaf(h, w[2], s2);
  }
#pragma unroll
  for (int o = 32; o >= 1; o >>= 1) {
    s0 += __shfl_xor(s0, o); s1 += __shfl_xor(s1, o); s2 += __shfl_xor(s2, o);
  }
  if (lane == 0) {
    out[bf * 3 + 0] = s0 + br[f * 3 + 0];
    out[bf * 3 + 1] = s1 + br[f * 3 + 1];
    out[bf * 3 + 2] = s2 + br[f * 3 + 2];
  }
}

extern "C" void kernel_launch(void* const* d_in, const int* in_sizes, int n_in,
                              void* d_out, int out_size, void* d_ws, size_t ws_size,
                              hipStream_t stream) {
  const float* x    = (const float*)d_in[0];
  const float* Wx   = (const float*)d_in[1];
  const float* Wh   = (const float*)d_in[2];
  const float* bias = (const float*)d_in[3];
  const float* Wr   = (const float*)d_in[4];
  const float* br   = (const float*)d_in[5];
  float* out = (float*)d_out;

  char* ws = (char*)d_ws;
  unsigned short* Wp  = (unsigned short*)ws;                        // 8,912,896 B
  unsigned short* xbt = (unsigned short*)(ws + 8912896);            // 16,777,216 B
  unsigned short* hbt = (unsigned short*)(ws + 8912896 + 16777216); // 1,048,576 B
  float* hf           = (float*)(ws + 8912896 + 16777216 + 1048576);// 1,048,576 B
  int* flags          = (int*)(ws + 8912896 + 16777216 + 1048576 + 1048576); // 16,384 B

  k_zero_flags<<<16, 256, 0, stream>>>(flags);
  k_pack_w<<<17 * 64, 256, 0, stream>>>(Wx, Wh, Wp);
  k_pack_x<<<4096, 256, 0, stream>>>(x, xbt);
  k_scan<<<256, 256, 0, stream>>>(Wp, xbt, hbt, hf, bias, flags);
  k_head<<<2048, 64, 0, stream>>>(hf, Wr, br, out);
}

// Round 5
// 4381.207 us; speedup vs baseline: 2.4150x; 2.4150x over previous
//
#include <hip/hip_runtime.h>
#include <hip/hip_bf16.h>

#define B_   256
#define T_   512
#define D_   64
#define H_   1024
#define NG   4096   // 4*H
#define KTOT 1088   // D + H
#define WPAD 1096   // +8 bf16 pad

typedef __attribute__((ext_vector_type(8)))  short short8;
typedef __attribute__((ext_vector_type(16))) float f32x16;

static __device__ __forceinline__ float tanh_clamped(float u) {
  u = fminf(fmaxf(u, -15.0f), 15.0f);
  float e = __expf(-2.0f * u);
  return (1.0f - e) / (1.0f + e);
}
static __device__ __forceinline__ unsigned short f2bf(float f) {
  union { float f; unsigned int u; } v; v.f = f;
  unsigned int r = (v.u + 0x7FFFu + ((v.u >> 16) & 1u)) >> 16; // RNE
  return (unsigned short)r;
}

__global__ void k_zero_flags(int* flags) {
  int gid = blockIdx.x * 256 + threadIdx.x;
  if (gid < 4096) flags[gid] = 0;
}

// Pack [Wx; Wh] -> Wp[n][k] bf16, n gate-interleaved: n = 4*j + gate, orig col = gate*1024 + j
__global__ void k_pack_w(const float* __restrict__ Wx, const float* __restrict__ Wh,
                         unsigned short* __restrict__ Wp) {
  __shared__ float tile[64][65];
  int nt = blockIdx.x & 63;   // 64 n-tiles
  int kt = blockIdx.x >> 6;   // 17 k-tiles
  int tx = threadIdx.x & 63, ty = threadIdx.x >> 6;
#pragma unroll
  for (int i = 0; i < 16; ++i) {
    int kl = i * 4 + ty;
    int k  = kt * 64 + kl;
    int n  = nt * 64 + tx;
    int oc = ((n & 3) << 10) | (n >> 2);
    float v = (k < D_) ? Wx[k * NG + oc] : Wh[(k - D_) * NG + oc];
    tile[kl][tx] = v;
  }
  __syncthreads();
#pragma unroll
  for (int i = 0; i < 16; ++i) {
    int nl = i * 4 + ty;
    int kl = tx;
    Wp[(size_t)(nt * 64 + nl) * KTOT + kt * 64 + kl] = f2bf(tile[kl][nl]);
  }
}

// Pack x (B,T,64) fp32 -> xbt[t][kk][b][8] bf16 (A-fragment friendly)
__global__ void k_pack_x(const float* __restrict__ x, unsigned short* __restrict__ xbt) {
  int gid = blockIdx.x * 256 + threadIdx.x;  // 1,048,576 chunks
  int b  = gid & 255;
  int kk = (gid >> 8) & 7;
  int t  = gid >> 11;
  const float* src = x + ((size_t)b * T_ + t) * 64 + kk * 8;
  short8 v;
#pragma unroll
  for (int i = 0; i < 8; ++i) v[i] = (short)f2bf(src[i]);
  *(short8*)(xbt + (size_t)gid * 8) = v;
}

__launch_bounds__(256, 1)
__global__ void k_scan(const unsigned short* __restrict__ Wp,
                       const unsigned short* __restrict__ xbt,
                       unsigned short* __restrict__ hbt,   // [2][128][256][8] bf16
                       float* __restrict__ hf,             // [256][1024] fp32 (t=511)
                       const float* __restrict__ bias,
                       int* __restrict__ flags) {
  __shared__ unsigned short Wl[64 * WPAD];  // 140,288 B
  const int tid  = threadIdx.x;
  const int bid  = blockIdx.x;
  const int m    = bid >> 6;     // 4 m-groups of 64 rows
  const int nt   = bid & 63;     // 64 interleaved-col tiles
  const int n0   = nt * 64;
  const int wave = tid >> 6;
  const int lane = tid & 63;
  const int wr = wave >> 1, wc = wave & 1;

  // Stage this block's 64 W columns into LDS (once)
  for (int i = tid; i < 64 * (KTOT / 8); i += 256) {
    int c  = i / (KTOT / 8);
    int kk = i - c * (KTOT / 8);
    short8 v = *(const short8*)(Wp + (size_t)(n0 + c) * KTOT + kk * 8);
    *(short8*)((char*)Wl + c * (WPAD * 2) + kk * 16) = v;
  }
  __syncthreads();

  const int khalf = lane >> 5;                 // 0/1: k-subblock of fragment
  const int rowA  = m * 64 + wr * 32 + (lane & 31);
  const int colB  = wc * 32 + (lane & 31);     // LDS-local col
  const int n     = n0 + colB;
  const int oc    = ((n & 3) << 10) | (n >> 2);
  const float bv  = bias[oc];
  const int s     = lane & 3;                  // gate: 0=i 1=f 2=g 3=o
  const int jH    = n >> 2;
  const char* WlB = (const char*)Wl + colB * (WPAD * 2) + khalf * 16;

  const int rowbase = m * 64 + wr * 32 + 4 * khalf;

  float c_state[16];
#pragma unroll
  for (int r = 0; r < 16; ++r) c_state[r] = 0.0f;

  // distributed flags: 64B-spaced, one per block, per m-group
  int* myflag = flags + (m * 64 + nt) * 16;
  int* pollp  = flags + (m * 64 + lane) * 16;

  const unsigned int voff0 = (unsigned)(khalf * 4096 + rowA * 16);  // bytes into h buffer

  for (int t = 0; t < T_; ++t) {
    f32x16 acc;
#pragma unroll
    for (int r = 0; r < 16; ++r) acc[r] = bv;

    // x-contribution (independent of h -> overlaps with waiting)
#pragma unroll
    for (int kt = 0; kt < 4; ++kt) {
      int kkx = t * 8 + kt * 2 + khalf;
      short8 a  = *(const short8*)(xbt + (size_t)kkx * 2048 + rowA * 8);
      short8 b8 = *(const short8*)(WlB + kt * 32);
      acc = __builtin_amdgcn_mfma_f32_32x32x16_bf16(a, b8, acc, 0, 0, 0);
    }

    if (t > 0) {
      __builtin_amdgcn_sched_barrier(0);  // pin x-loads/MFMAs above
      // wave 0: each lane polls one producer's flag; exit when all >= t
      if (wave == 0) {
        for (;;) {
          int v = __hip_atomic_load(pollp, __ATOMIC_RELAXED, __HIP_MEMORY_SCOPE_AGENT);
          if (__all(v >= t)) break;
          __builtin_amdgcn_s_sleep(1);
        }
      }
      __syncthreads();
      // h lives at the coherence point (LLC): producers stored sc0 sc1, we load
      // sc0 sc1 (bypass stale L1/L2). No buffer_inv / wbl2 fences anywhere.
      const unsigned short* hsrc = hbt + (size_t)((t + 1) & 1) * 128 * 2048;

      f32x16 acc1;
#pragma unroll
      for (int r = 0; r < 16; ++r) acc1[r] = 0.0f;

      // ---- phase 1: fragments 0..31 (128 arch VGPRs in flight, no spill) ----
      short8 aH[32];
#pragma unroll
      for (int j = 0; j < 32; ++j) {
        unsigned int vo = voff0 + (unsigned)(j * 8192);
        asm volatile("global_load_dwordx4 %0, %1, %2 sc0 sc1"
                     : "=v"(aH[j]) : "v"(vo), "s"(hsrc));
      }
      asm volatile("s_waitcnt vmcnt(0)" ::: "memory");
      __builtin_amdgcn_sched_barrier(0);
#pragma unroll
      for (int j = 0; j < 32; j += 2) {
        short8 b0 = *(const short8*)(WlB + 128 + j * 32);
        short8 b1 = *(const short8*)(WlB + 128 + (j + 1) * 32);
        acc  = __builtin_amdgcn_mfma_f32_32x32x16_bf16(aH[j],     b0, acc,  0, 0, 0);
        acc1 = __builtin_amdgcn_mfma_f32_32x32x16_bf16(aH[j + 1], b1, acc1, 0, 0, 0);
      }

      // ---- phase 2: fragments 32..63 (reuse aH registers) ----
#pragma unroll
      for (int j = 0; j < 32; ++j) {
        unsigned int vo = voff0 + (unsigned)((32 + j) * 8192);
        asm volatile("global_load_dwordx4 %0, %1, %2 sc0 sc1"
                     : "=v"(aH[j]) : "v"(vo), "s"(hsrc));
      }
      asm volatile("s_waitcnt vmcnt(0)" ::: "memory");
      __builtin_amdgcn_sched_barrier(0);
#pragma unroll
      for (int j = 0; j < 32; j += 2) {
        short8 b0 = *(const short8*)(WlB + 128 + (32 + j) * 32);
        short8 b1 = *(const short8*)(WlB + 128 + (33 + j) * 32);
        acc  = __builtin_amdgcn_mfma_f32_32x32x16_bf16(aH[j],     b0, acc,  0, 0, 0);
        acc1 = __builtin_amdgcn_mfma_f32_32x32x16_bf16(aH[j + 1], b1, acc1, 0, 0, 0);
      }
#pragma unroll
      for (int r = 0; r < 16; ++r) acc[r] += acc1[r];
    }

    // gates + state update; lanes 4j..4j+3 hold i,f,g,o of (row, j)
    unsigned short* hdst = hbt + (size_t)(t & 1) * 128 * 2048;
#pragma unroll
    for (int r = 0; r < 16; ++r) {
      float z  = acc[r];
      float u  = (s == 2) ? z : 0.5f * z;
      float tv = tanh_clamped(u);
      float av = (s == 2) ? tv : 0.5f * (1.0f + tv);
      float x1 = __shfl_xor(av, 1);
      float x2 = __shfl_xor(av, 2);
      float x3 = __shfl_xor(av, 3);
      float i_ = (s == 0) ? av : (s == 1) ? x1 : (s == 2) ? x2 : x3;
      float f_ = (s == 1) ? av : (s == 0) ? x1 : (s == 3) ? x2 : x3;
      float g_ = (s == 2) ? av : (s == 3) ? x1 : (s == 0) ? x2 : x3;
      float o_ = (s == 3) ? av : (s == 2) ? x1 : (s == 1) ? x2 : x3;
      float cn = f_ * c_state[r] + i_ * g_;
      c_state[r] = cn;
      float hn = o_ * tanh_clamped(cn);
      if (s == 0) {
        int row = rowbase + (r & 3) + 8 * (r >> 2);
        if (t < T_ - 1) {
          unsigned int vo = (unsigned)((jH >> 3) * 4096 + row * 16 + (jH & 7) * 2);
          unsigned int hv = f2bf(hn);
          asm volatile("global_store_short %0, %1, %2 sc0 sc1"
                       :: "v"(vo), "v"(hv), "s"(hdst) : "memory");
        } else {
          hf[(size_t)row * H_ + jH] = hn;
        }
      }
    }

    // drain own sc stores to the coherence point, then publish
    asm volatile("s_waitcnt vmcnt(0)" ::: "memory");
    if (t < T_ - 1) {
      __syncthreads();  // all waves drained before flag release
      if (tid == 0) {
        __hip_atomic_store(myflag, t + 1, __ATOMIC_RELAXED, __HIP_MEMORY_SCOPE_AGENT);
      }
    }
  }
}

__global__ void k_head(const float* __restrict__ hf, const float* __restrict__ Wr,
                       const float* __restrict__ br, float* __restrict__ out) {
  int bf = blockIdx.x;            // b*8 + f
  int b = bf >> 3, f = bf & 7;
  int lane = threadIdx.x;
  float s0 = 0.f, s1 = 0.f, s2 = 0.f;
  for (int j = lane; j < H_; j += 64) {
    float h = hf[(size_t)b * H_ + j];
    const float* w = Wr + ((size_t)f * H_ + j) * 3;
    s0 = fmaf(h, w[0], s0); s1 = fmaf(h, w[1], s1); s2 = fmaf(h, w[2], s2);
  }
#pragma unroll
  for (int o = 32; o >= 1; o >>= 1) {
    s0 += __shfl_xor(s0, o); s1 += __shfl_xor(s1, o); s2 += __shfl_xor(s2, o);
  }
  if (lane == 0) {
    out[bf * 3 + 0] = s0 + br[f * 3 + 0];
    out[bf * 3 + 1] = s1 + br[f * 3 + 1];
    out[bf * 3 + 2] = s2 + br[f * 3 + 2];
  }
}

extern "C" void kernel_launch(void* const* d_in, const int* in_sizes, int n_in,
                              void* d_out, int out_size, void* d_ws, size_t ws_size,
                              hipStream_t stream) {
  const float* x    = (const float*)d_in[0];
  const float* Wx   = (const float*)d_in[1];
  const float* Wh   = (const float*)d_in[2];
  const float* bias = (const float*)d_in[3];
  const float* Wr   = (const float*)d_in[4];
  const float* br   = (const float*)d_in[5];
  float* out = (float*)d_out;

  char* ws = (char*)d_ws;
  unsigned short* Wp  = (unsigned short*)ws;                        // 8,912,896 B
  unsigned short* xbt = (unsigned short*)(ws + 8912896);            // 16,777,216 B
  unsigned short* hbt = (unsigned short*)(ws + 8912896 + 16777216); // 1,048,576 B
  float* hf           = (float*)(ws + 8912896 + 16777216 + 1048576);// 1,048,576 B
  int* flags          = (int*)(ws + 8912896 + 16777216 + 1048576 + 1048576); // 16,384 B

  k_zero_flags<<<16, 256, 0, stream>>>(flags);
  k_pack_w<<<17 * 64, 256, 0, stream>>>(Wx, Wh, Wp);
  k_pack_x<<<4096, 256, 0, stream>>>(x, xbt);
  k_scan<<<256, 256, 0, stream>>>(Wp, xbt, hbt, hf, bias, flags);
  k_head<<<2048, 64, 0, stream>>>(hf, Wr, br, out);
}